// Round 5
// baseline (357.489 us; speedup 1.0000x reference)
//
#include <hip/hip_runtime.h>
#include <math.h>

// ---------------- problem constants ----------------
#define BD   8       // batch
#define TT   4096    // time
#define DD   1024    // feature dim
#define HH   8       // heads
#define KK   6       // picks
// d_out layout (floats): rep | indices | combined | dist | mu_q | sigma_q | loss
#define OFF_REP   0
#define OFF_IDX   49152
#define OFF_COMB  49200
#define OFF_DIST  81968
#define OFF_MU    114736
#define OFF_SG    122928
#define OFF_LOSS  131120
// ws layout (floats)
#define WS_X1     0        // 2*8*1024
#define WS_H      16384    // 2*8*1024
#define WS_Q      32768    // 8*1024
#define WS_P      40960    // 8*8*1024
#define WS_SUMS   106496   // 64  (per b,h sum of exp(score))
#define WS_ISIG   106560   // 8*1024
#define WS_ES     114752   // 8*8*4096  (exp(score))

#define INV_SQRT_DH 0.08838834764831845f  // 1/sqrt(128)

__device__ __forceinline__ float softplus_f(float x) {
  return fmaxf(x, 0.0f) + log1pf(expf(-fabsf(x)));
}

// ---- shared GEMV core: out[b,row] = in[b,:] . W[row,:]  (8 batches, wave per row)
__device__ __forceinline__ void gemv_rows_core(const float* __restrict__ in,
                                               const float* __restrict__ W,
                                               int row, float (*s_in)[DD], float acc[8]) {
  int tid = threadIdx.x;
  const float4* in4 = (const float4*)in;
  float4* s4 = (float4*)&s_in[0][0];
  for (int i = tid; i < 2048; i += 256) s4[i] = in4[i];
  __syncthreads();
  int lane = tid & 63;
  const float4* wr4 = (const float4*)(W + (size_t)row * DD);
#pragma unroll
  for (int b = 0; b < 8; ++b) acc[b] = 0.0f;
#pragma unroll
  for (int i = 0; i < 4; ++i) {
    int d4 = i * 64 + lane;
    float4 w4 = wr4[d4];
#pragma unroll
    for (int b = 0; b < 8; ++b) {
      float4 q4 = ((const float4*)&s_in[b][0])[d4];
      acc[b] += w4.x * q4.x + w4.y * q4.y + w4.z * q4.z + w4.w * q4.w;
    }
  }
#pragma unroll
  for (int off = 32; off; off >>= 1)
#pragma unroll
    for (int b = 0; b < 8; ++b) acc[b] += __shfl_xor(acc[b], off, 64);
}

// x1[path][b][row] = qe[b]·W{path}[row] + bias
__global__ __launch_bounds__(256) void k_gemv_pre(const float* __restrict__ qe,
    const float* __restrict__ W0, const float* __restrict__ W1,
    const float* __restrict__ b0, const float* __restrict__ b1, float* __restrict__ x1) {
  __shared__ float s_in[8][DD];
  int path = blockIdx.x >> 8;
  int row = (blockIdx.x & 255) * 4 + (threadIdx.x >> 6);
  const float* W = path ? W1 : W0;
  const float* bb = path ? b1 : b0;
  float acc[8];
  gemv_rows_core(qe, W, row, s_in, acc);
  if ((threadIdx.x & 63) == 0) {
    float bv = bb[row];
#pragma unroll
    for (int b = 0; b < 8; ++b) x1[path * 8192 + b * DD + row] = acc[b] + bv;
  }
}

// LN + relu per (path,b) row of 1024 — single-pass (sum, sumsq) + shuffle reduce
__global__ __launch_bounds__(256) void k_ln(const float* __restrict__ x1,
    const float* __restrict__ g0, const float* __restrict__ be0,
    const float* __restrict__ g1, const float* __restrict__ be1, float* __restrict__ h) {
  int path = blockIdx.x >> 3, b = blockIdx.x & 7;
  const float4* x4 = (const float4*)(x1 + path * 8192 + b * DD);
  const float4* g4 = (const float4*)(path ? g1 : g0);
  const float4* be4 = (const float4*)(path ? be1 : be0);
  int tid = threadIdx.x, wave = tid >> 6, lane = tid & 63;
  __shared__ float ws1[4], ws2[4];
  float4 v = x4[tid];
  float s = v.x + v.y + v.z + v.w;
  float s2 = v.x * v.x + v.y * v.y + v.z * v.z + v.w * v.w;
#pragma unroll
  for (int off = 32; off; off >>= 1) {
    s += __shfl_xor(s, off, 64);
    s2 += __shfl_xor(s2, off, 64);
  }
  if (lane == 0) { ws1[wave] = s; ws2[wave] = s2; }
  __syncthreads();
  s = ws1[0] + ws1[1] + ws1[2] + ws1[3];
  s2 = ws2[0] + ws2[1] + ws2[2] + ws2[3];
  float mean = s * (1.0f / 1024.0f);
  float var = s2 * (1.0f / 1024.0f) - mean * mean;
  float inv = 1.0f / sqrtf(var + 1e-5f);
  float4 g = g4[tid], be = be4[tid], o;
  o.x = fmaxf((v.x - mean) * inv * g.x + be.x, 0.0f);
  o.y = fmaxf((v.y - mean) * inv * g.y + be.y, 0.0f);
  o.z = fmaxf((v.z - mean) * inv * g.z + be.z, 0.0f);
  o.w = fmaxf((v.w - mean) * inv * g.w + be.w, 0.0f);
  ((float4*)(h + path * 8192 + b * DD))[tid] = o;
}

// path0: mu_q; path1: sigma_q = softplus+1e-6, isig = 1/sigma
__global__ __launch_bounds__(256) void k_gemv_mid(const float* __restrict__ h,
    const float* __restrict__ W0, const float* __restrict__ W1,
    const float* __restrict__ b0, const float* __restrict__ b1,
    float* __restrict__ mu_out, float* __restrict__ sg_out, float* __restrict__ isig) {
  __shared__ float s_in[8][DD];
  int path = blockIdx.x >> 8;
  int row = (blockIdx.x & 255) * 4 + (threadIdx.x >> 6);
  const float* W = path ? W1 : W0;
  const float* bb = path ? b1 : b0;
  float acc[8];
  gemv_rows_core(h + path * 8192, W, row, s_in, acc);
  if ((threadIdx.x & 63) == 0) {
    float bv = bb[row];
#pragma unroll
    for (int b = 0; b < 8; ++b) {
      float v = acc[b] + bv;
      if (path == 0) {
        mu_out[b * DD + row] = v;
      } else {
        float sp = softplus_f(v) + 1e-6f;
        sg_out[b * DD + row] = sp;
        isig[b * DD + row] = 1.0f / sp;
      }
    }
  }
}

// q[b,row] = mu_q[b]·wq[row] + bq[row]   (wq = in_w rows 0..1023)
__global__ __launch_bounds__(256) void k_gemv_q(const float* __restrict__ mu_q,
    const float* __restrict__ in_w, const float* __restrict__ in_b, float* __restrict__ q) {
  __shared__ float s_in[8][DD];
  int row = blockIdx.x * 4 + (threadIdx.x >> 6);
  float acc[8];
  gemv_rows_core(mu_q, in_w, row, s_in, acc);
  if ((threadIdx.x & 63) == 0) {
    float bv = in_b[row];
#pragma unroll
    for (int b = 0; b < 8; ++b) q[b * DD + row] = acc[b] + bv;
  }
}

// p[b,h,j] = (sum_r q[b,h*128+r]*wk[h*128+r,j]) / sqrt(128)
// NOTE: the k-bias term q·bk is constant over t -> softmax-invariant -> dropped.
// Block 0 also zero-inits the exp-sum accumulator and loss (stream-ordered before k_main).
// r-loop unrolled 8x: 8 loads in flight instead of 1 (was a 128-deep serial chain).
__global__ __launch_bounds__(256) void k_p(const float* __restrict__ q,
    const float* __restrict__ in_w, float* __restrict__ p,
    float* __restrict__ sums, float* __restrict__ loss_out) {
  if (blockIdx.x == 0) {
    if (threadIdx.x < 64) sums[threadIdx.x] = 0.0f;
    else if (threadIdx.x == 64) loss_out[0] = 0.0f;
  }
  int hh = blockIdx.x >> 2;
  int j0 = (blockIdx.x & 3) * 256;
  __shared__ float qh[8][128];
  for (int i = threadIdx.x; i < 1024; i += 256) {
    int b = i >> 7, r = i & 127;
    qh[b][r] = q[b * DD + hh * 128 + r];
  }
  __syncthreads();
  const float* wbase = in_w + (size_t)(DD + hh * 128) * DD + j0 + threadIdx.x;
  float acc[8];
#pragma unroll
  for (int b = 0; b < 8; ++b) acc[b] = 0.0f;
#pragma unroll 8
  for (int r = 0; r < 128; ++r) {
    float w = wbase[(size_t)r * DD];
#pragma unroll
    for (int b = 0; b < 8; ++b) acc[b] += qh[b][r] * w;
  }
#pragma unroll
  for (int b = 0; b < 8; ++b) p[(b * HH + hh) * DD + j0 + threadIdx.x] = acc[b] * INV_SQRT_DH;
}

// Big streaming pass: dist[b,t] (f64 acc) and es[b,h,t] = exp(score) + per-(b,h) sums.
// 1024 blocks x 512 threads (8 waves), 32 rows/block: grid/CU = 4 blocks AND
// LDS 4 x 40960 = 163840 B = full CU -> 32 waves/CU resident (8/SIMD), double
// the latency hiding of the 16-wave/CU configs that all plateaued at ~79 us.
// Lane remap: each 16-lane quarter owns ONE t row (quarter = lane>>4, sub = lane&15);
// reduction is 4 butterfly levels over 9 values. Head h owned by lane sub==h.
// VGPR 28 (r4 build) << 64-reg cap of launch_bounds(512,8) -> no spill.
__global__ __launch_bounds__(512, 8) void k_main(const float* __restrict__ video,
    const float* __restrict__ mu_q, const float* __restrict__ isig,
    const float* __restrict__ p,
    float* __restrict__ dist_out, float* __restrict__ es, float* __restrict__ sums) {
  __shared__ float s_mu[DD];     // 4 KB
  __shared__ float s_is[DD];     // 4 KB
  __shared__ float s_p[HH][DD];  // 32 KB  (total 40960 B)
  int b = blockIdx.x >> 7;
  int group = blockIdx.x & 127;
  int tid = threadIdx.x;
  int wave = tid >> 6, lane = tid & 63;
  int quarter = lane >> 4;   // which of the wave's 4 t-rows
  int sub = lane & 15;       // d-slice within the quarter
  float4* s_mu4 = (float4*)s_mu;
  float4* s_is4 = (float4*)s_is;
  float4* s_p4 = (float4*)&s_p[0][0];
  if (tid < 256) {
    s_mu4[tid] = ((const float4*)(mu_q + b * DD))[tid];
    s_is4[tid] = ((const float4*)(isig + b * DD))[tid];
  }
  const float4* pg4 = (const float4*)(p + b * HH * DD);
  for (int i = tid; i < 2048; i += 512) s_p4[i] = pg4[i];
  __syncthreads();

  int t = group * 32 + wave * 4 + quarter;
  const float4* v4 = (const float4*)(video + ((size_t)(b * TT + t)) * DD);

  double dacc = 0.0;
  float sacc[8];
#pragma unroll
  for (int hh = 0; hh < 8; ++hh) sacc[hh] = 0.0f;

#pragma unroll 4
  for (int i = 0; i < 16; ++i) {
    int d4 = i * 16 + sub;
    float4 vv = v4[d4];
    float4 mu4 = s_mu4[d4];
    float4 is4 = s_is4[d4];
    float dx = vv.x - mu4.x;
    float dy = vv.y - mu4.y;
    float dz = vv.z - mu4.z;
    float dw = vv.w - mu4.w;
    float e = dx * dx * is4.x + dy * dy * is4.y + dz * dz * is4.z + dw * dw * is4.w;
    dacc += (double)e;
#pragma unroll
    for (int hh = 0; hh < 8; ++hh) {
      float4 pp = ((const float4*)&s_p[hh][0])[d4];
      sacc[hh] += pp.x * vv.x + pp.y * vv.y + pp.z * vv.z + pp.w * vv.w;
    }
  }

  // butterfly within each 16-lane quarter (offsets 1,2,4,8)
#pragma unroll
  for (int off = 1; off < 16; off <<= 1) {
    dacc += __shfl_xor(dacc, off, 64);
#pragma unroll
    for (int hh = 0; hh < 8; ++hh) sacc[hh] += __shfl_xor(sacc[hh], off, 64);
  }

  if (sub == 0) dist_out[b * TT + t] = (float)dacc;
  float esum_acc = 0.0f;  // valid on lanes with sub<8 (head = sub)
  if (sub < 8) {
    // static selection ladder: lane sub owns head sub
    float v = sacc[0];
#pragma unroll
    for (int hh = 1; hh < 8; ++hh) v = (sub == hh) ? sacc[hh] : v;
    float ev = expf(v);
    es[(size_t)(b * HH + sub) * TT + t] = ev;
    esum_acc = ev;
  }

  // combine esum across quarters (same sub: lanes l, l^16, l^32, l^48)
  esum_acc += __shfl_xor(esum_acc, 16, 64);
  esum_acc += __shfl_xor(esum_acc, 32, 64);
  if (lane < 8) atomicAdd(&sums[b * HH + lane], esum_acc);
}

// Fused epilogue, one 1024-thread block per b:
//   attn mean from precomputed es/sums (single read) -> radix-select median
//   (wave-private histograms) -> combined (regs) -> greedy-K (all-register) ->
//   gather rep -> loss partial (atomicAdd).
__global__ __launch_bounds__(1024) void k_epilogue(const float* __restrict__ es,
    const float* __restrict__ sums,
    const float* __restrict__ dist, const float* __restrict__ video,
    float* __restrict__ comb_out, float* __restrict__ idx_out,
    float* __restrict__ rep, float* __restrict__ loss_out) {
  int b = blockIdx.x;
  int tid = threadIdx.x;
  int wave = tid >> 6, lane = tid & 63;
  __shared__ float s_dist[TT];            // 16 KB
  __shared__ float s_hs[HH];
  __shared__ unsigned whist[16][256];     // 16 KB wave-private histograms
  __shared__ unsigned wsum[4];
  __shared__ unsigned s_sel;
  __shared__ int s_kk;
  __shared__ float wv[16];
  __shared__ int wi[16];
  __shared__ int s_pick;
  __shared__ float wdiv[16];
  __shared__ float repb[KK * DD];         // 24 KB

  if (tid < HH) s_hs[tid] = 1.0f / sums[b * HH + tid];
  __syncthreads();

  // ---- attn mean + stage dist (one float4 per thread) ----
  float4 d4 = ((const float4*)(dist + b * TT))[tid];
  ((float4*)s_dist)[tid] = d4;
  float4 aw = make_float4(0.f, 0.f, 0.f, 0.f);
#pragma unroll
  for (int h = 0; h < HH; ++h) {
    float4 e4 = ((const float4*)(es + ((size_t)(b * HH + h)) * TT))[tid];
    float is = s_hs[h];
    aw.x += e4.x * is;
    aw.y += e4.y * is;
    aw.z += e4.z * is;
    aw.w += e4.w * is;
  }
  aw.x *= 0.125f; aw.y *= 0.125f; aw.z *= 0.125f; aw.w *= 0.125f;
  uint4 keys;
  keys.x = __float_as_uint(d4.x);
  keys.y = __float_as_uint(d4.y);
  keys.z = __float_as_uint(d4.z);
  keys.w = __float_as_uint(d4.w);

  // ---- radix-select median: rank 2047 (positive floats ~ uint order) ----
  unsigned prefix = 0;
  int kk = (TT - 1) / 2;
  for (int pass = 0; pass < 4; ++pass) {
    int shift = 24 - 8 * pass;
    ((uint4*)whist)[tid] = make_uint4(0u, 0u, 0u, 0u);  // 1024 threads x 16B = 16 KB
    __syncthreads();
    {
      unsigned karr[4] = {keys.x, keys.y, keys.z, keys.w};
#pragma unroll
      for (int j = 0; j < 4; ++j) {
        unsigned key = karr[j];
        bool ok = (pass == 0) || ((key >> (shift + 8)) == prefix);
        if (ok) atomicAdd(&whist[wave][(key >> shift) & 255], 1u);
      }
    }
    __syncthreads();
    unsigned hcnt = 0, inc = 0;
    if (tid < 256) {
#pragma unroll
      for (int w = 0; w < 16; ++w) hcnt += whist[w][tid];
      inc = hcnt;
#pragma unroll
      for (int off = 1; off < 64; off <<= 1) {
        unsigned v = __shfl_up(inc, off, 64);
        if (lane >= off) inc += v;
      }
      if (lane == 63) wsum[wave] = inc;
    }
    __syncthreads();
    if (tid < 256) {
      unsigned base = 0;
      for (int w = 0; w < wave; ++w) base += wsum[w];
      unsigned excl = base + inc - hcnt;
      if ((int)excl <= kk && kk < (int)(excl + hcnt)) {
        s_sel = (prefix << 8) | (unsigned)tid;
        s_kk = kk - (int)excl;
      }
    }
    __syncthreads();
    prefix = s_sel;
    kk = s_kk;
    __syncthreads();
  }
  float med = __uint_as_float(prefix);

  // ---- combined (registers) + global write ----
  float4 cb;
  cb.x = expf(-fabsf(d4.x - med) / 0.1f) * aw.x;
  cb.y = expf(-fabsf(d4.y - med) / 0.1f) * aw.y;
  cb.z = expf(-fabsf(d4.z - med) / 0.1f) * aw.z;
  cb.w = expf(-fabsf(d4.w - med) / 0.1f) * aw.w;
  ((float4*)(comb_out + b * TT))[tid] = cb;

  // ---- greedy K-selection, all-register (first-occurrence argmax) ----
  float4 md = make_float4(0.f, 0.f, 0.f, 0.f);
  int i0 = tid * 4;
  int picks[KK];
  for (int k = 0; k < KK; ++k) {
    float carr[4] = {cb.x, cb.y, cb.z, cb.w};
    float marr[4] = {md.x, md.y, md.z, md.w};
    float best = -INFINITY; int bi = 1 << 30;
#pragma unroll
    for (int j = 0; j < 4; ++j) {
      float cv = carr[j];
      float sc = (k == 0) ? cv : ((cv < 0.0f) ? -INFINITY : marr[j] * cv);
      if (sc > best) { best = sc; bi = i0 + j; }
    }
#pragma unroll
    for (int off = 32; off; off >>= 1) {
      float ov = __shfl_xor(best, off, 64);
      int oi = __shfl_xor(bi, off, 64);
      if (ov > best || (ov == best && oi < bi)) { best = ov; bi = oi; }
    }
    if (lane == 0) { wv[wave] = best; wi[wave] = bi; }
    __syncthreads();
    if (tid == 0) {
      float bb2 = wv[0]; int ii = wi[0];
#pragma unroll
      for (int w = 1; w < 16; ++w)
        if (wv[w] > bb2 || (wv[w] == bb2 && wi[w] < ii)) { bb2 = wv[w]; ii = wi[w]; }
      s_pick = ii;
    }
    __syncthreads();
    int pick = s_pick;
    picks[k] = pick;
    // mask in registers (owning thread only) + update min-dist in registers
    if ((pick >> 2) == tid) {
      int j = pick & 3;
      if (j == 0) cb.x = -1.0f; else if (j == 1) cb.y = -1.0f;
      else if (j == 2) cb.z = -1.0f; else cb.w = -1.0f;
    }
    float dn0 = fabsf((float)(i0 + 0 - pick));
    float dn1 = fabsf((float)(i0 + 1 - pick));
    float dn2 = fabsf((float)(i0 + 2 - pick));
    float dn3 = fabsf((float)(i0 + 3 - pick));
    if (k == 0) { md.x = dn0; md.y = dn1; md.z = dn2; md.w = dn3; }
    else { md.x = fminf(md.x, dn0); md.y = fminf(md.y, dn1);
           md.z = fminf(md.z, dn2); md.w = fminf(md.w, dn3); }
  }
  if (tid < KK) idx_out[b * KK + tid] = (float)picks[tid];

  // ---- gather rep ----
  float4* repb4 = (float4*)repb;
  float4* rep4 = (float4*)(rep + (size_t)b * KK * DD);
  for (int e = tid; e < KK * (DD / 4); e += 1024) {
    int k = e >> 8, dd4 = e & 255;
    const float4* vrow = (const float4*)(video + ((size_t)(b * TT + picks[k])) * DD);
    float4 v = vrow[dd4];
    rep4[(size_t)k * (DD / 4) + dd4] = v;
    repb4[e] = v;
  }
  __syncthreads();

  // ---- diversity: 15 pairs over 16 waves ----
  const int pk[15] = {0,0,0,0,0,1,1,1,1,2,2,2,3,3,4};
  const int pj[15] = {1,2,3,4,5,2,3,4,5,3,4,5,4,5,5};
  float divacc = 0.0f;
  if (wave < 15) {
    int a = pk[wave], j = pj[wave];
    float part = 0.0f;
    for (int d = lane; d < DD; d += 64) part += repb[a * DD + d] * repb[j * DD + d];
#pragma unroll
    for (int off = 32; off; off >>= 1) part += __shfl_xor(part, off, 64);
    if (lane == 0) divacc = part * part;
  }
  if (lane == 0) wdiv[wave] = (wave < 15) ? divacc : 0.0f;
  __syncthreads();

  if (tid == 0) {
    float div = 0.0f;
#pragma unroll
    for (int w = 0; w < 15; ++w) div += wdiv[w];
    float rd[KK], srt[KK];
#pragma unroll
    for (int k = 0; k < KK; ++k) { rd[k] = s_dist[picks[k]]; srt[k] = rd[k]; }
    for (int a = 1; a < KK; ++a) {
      float key = srt[a]; int b2 = a - 1;
      while (b2 >= 0 && srt[b2] > key) { srt[b2 + 1] = srt[b2]; --b2; }
      srt[b2 + 1] = key;
    }
    float target = srt[(KK - 1) / 2];
    float ell = 0.0f, cons = 0.0f;
#pragma unroll
    for (int k = 0; k < KK; ++k) { float d = rd[k] - target; ell += d * d; cons += rd[k]; }
    float partial = ell * (1.0f / 48.0f) + 0.1f * cons * (1.0f / 48.0f) + 0.05f * div * (1.0f / 288.0f);
    atomicAdd(loss_out, partial);
  }
}

extern "C" void kernel_launch(void* const* d_in, const int* in_sizes, int n_in,
                              void* d_out, int out_size, void* d_ws, size_t ws_size,
                              hipStream_t stream) {
  const float* video = (const float*)d_in[0];
  const float* qe    = (const float*)d_in[1];
  const float* mu_w1 = (const float*)d_in[2];
  const float* mu_b1 = (const float*)d_in[3];
  const float* mu_g  = (const float*)d_in[4];
  const float* mu_be = (const float*)d_in[5];
  const float* mu_w2 = (const float*)d_in[6];
  const float* mu_b2 = (const float*)d_in[7];
  const float* sg_w1 = (const float*)d_in[8];
  const float* sg_b1 = (const float*)d_in[9];
  const float* sg_g  = (const float*)d_in[10];
  const float* sg_be = (const float*)d_in[11];
  const float* sg_w2 = (const float*)d_in[12];
  const float* sg_b2 = (const float*)d_in[13];
  const float* in_w  = (const float*)d_in[14];
  const float* in_b  = (const float*)d_in[15];
  float* out = (float*)d_out;
  float* ws  = (float*)d_ws;

  k_gemv_pre<<<512, 256, 0, stream>>>(qe, mu_w1, sg_w1, mu_b1, sg_b1, ws + WS_X1);
  k_ln<<<16, 256, 0, stream>>>(ws + WS_X1, mu_g, mu_be, sg_g, sg_be, ws + WS_H);
  k_gemv_mid<<<512, 256, 0, stream>>>(ws + WS_H, mu_w2, sg_w2, mu_b2, sg_b2,
                                      out + OFF_MU, out + OFF_SG, ws + WS_ISIG);
  k_gemv_q<<<256, 256, 0, stream>>>(out + OFF_MU, in_w, in_b, ws + WS_Q);
  k_p<<<32, 256, 0, stream>>>(ws + WS_Q, in_w, ws + WS_P, ws + WS_SUMS, out + OFF_LOSS);
  k_main<<<1024, 512, 0, stream>>>(video, out + OFF_MU, ws + WS_ISIG, ws + WS_P,
                                   out + OFF_DIST, ws + WS_ES, ws + WS_SUMS);
  k_epilogue<<<8, 1024, 0, stream>>>(ws + WS_ES, ws + WS_SUMS, out + OFF_DIST, video,
                                     out + OFF_COMB, out + OFF_IDX, out + OFF_REP, out + OFF_LOSS);
}

// Round 7
// 323.149 us; speedup vs baseline: 1.1063x; 1.1063x over previous
//
#include <hip/hip_runtime.h>
#include <math.h>

// ---------------- problem constants ----------------
#define BD   8       // batch
#define TT   4096    // time
#define DD   1024    // feature dim
#define HH   8       // heads
#define KK   6       // picks
// d_out layout (floats): rep | indices | combined | dist | mu_q | sigma_q | loss
#define OFF_REP   0
#define OFF_IDX   49152
#define OFF_COMB  49200
#define OFF_DIST  81968
#define OFF_MU    114736
#define OFF_SG    122928
#define OFF_LOSS  131120
// ws layout (floats)
#define WS_X1     0        // 2*8*1024
#define WS_H      16384    // 2*8*1024
#define WS_Q      32768    // 8*1024
#define WS_P      40960    // 8*8*1024
#define WS_SUMS   106496   // 64  (per b,h sum of exp(score))
#define WS_ISIG   106560   // 8*1024
#define WS_ES     114752   // 8*8*4096  (exp(score))

#define INV_SQRT_DH 0.08838834764831845f  // 1/sqrt(128)

typedef float floatx4 __attribute__((ext_vector_type(4)));  // native vec for NT loads

__device__ __forceinline__ float softplus_f(float x) {
  return fmaxf(x, 0.0f) + log1pf(expf(-fabsf(x)));
}

// ---- shared GEMV core: out[b,row] = in[b,:] . W[row,:]  (8 batches, wave per row)
__device__ __forceinline__ void gemv_rows_core(const float* __restrict__ in,
                                               const float* __restrict__ W,
                                               int row, float (*s_in)[DD], float acc[8]) {
  int tid = threadIdx.x;
  const float4* in4 = (const float4*)in;
  float4* s4 = (float4*)&s_in[0][0];
  for (int i = tid; i < 2048; i += 256) s4[i] = in4[i];
  __syncthreads();
  int lane = tid & 63;
  const float4* wr4 = (const float4*)(W + (size_t)row * DD);
#pragma unroll
  for (int b = 0; b < 8; ++b) acc[b] = 0.0f;
#pragma unroll
  for (int i = 0; i < 4; ++i) {
    int d4 = i * 64 + lane;
    float4 w4 = wr4[d4];
#pragma unroll
    for (int b = 0; b < 8; ++b) {
      float4 q4 = ((const float4*)&s_in[b][0])[d4];
      acc[b] += w4.x * q4.x + w4.y * q4.y + w4.z * q4.z + w4.w * q4.w;
    }
  }
#pragma unroll
  for (int off = 32; off; off >>= 1)
#pragma unroll
    for (int b = 0; b < 8; ++b) acc[b] += __shfl_xor(acc[b], off, 64);
}

// x1[path][b][row] = qe[b]·W{path}[row] + bias
__global__ __launch_bounds__(256) void k_gemv_pre(const float* __restrict__ qe,
    const float* __restrict__ W0, const float* __restrict__ W1,
    const float* __restrict__ b0, const float* __restrict__ b1, float* __restrict__ x1) {
  __shared__ float s_in[8][DD];
  int path = blockIdx.x >> 8;
  int row = (blockIdx.x & 255) * 4 + (threadIdx.x >> 6);
  const float* W = path ? W1 : W0;
  const float* bb = path ? b1 : b0;
  float acc[8];
  gemv_rows_core(qe, W, row, s_in, acc);
  if ((threadIdx.x & 63) == 0) {
    float bv = bb[row];
#pragma unroll
    for (int b = 0; b < 8; ++b) x1[path * 8192 + b * DD + row] = acc[b] + bv;
  }
}

// LN + relu per (path,b) row of 1024 — single-pass (sum, sumsq) + shuffle reduce
__global__ __launch_bounds__(256) void k_ln(const float* __restrict__ x1,
    const float* __restrict__ g0, const float* __restrict__ be0,
    const float* __restrict__ g1, const float* __restrict__ be1, float* __restrict__ h) {
  int path = blockIdx.x >> 3, b = blockIdx.x & 7;
  const float4* x4 = (const float4*)(x1 + path * 8192 + b * DD);
  const float4* g4 = (const float4*)(path ? g1 : g0);
  const float4* be4 = (const float4*)(path ? be1 : be0);
  int tid = threadIdx.x, wave = tid >> 6, lane = tid & 63;
  __shared__ float ws1[4], ws2[4];
  float4 v = x4[tid];
  float s = v.x + v.y + v.z + v.w;
  float s2 = v.x * v.x + v.y * v.y + v.z * v.z + v.w * v.w;
#pragma unroll
  for (int off = 32; off; off >>= 1) {
    s += __shfl_xor(s, off, 64);
    s2 += __shfl_xor(s2, off, 64);
  }
  if (lane == 0) { ws1[wave] = s; ws2[wave] = s2; }
  __syncthreads();
  s = ws1[0] + ws1[1] + ws1[2] + ws1[3];
  s2 = ws2[0] + ws2[1] + ws2[2] + ws2[3];
  float mean = s * (1.0f / 1024.0f);
  float var = s2 * (1.0f / 1024.0f) - mean * mean;
  float inv = 1.0f / sqrtf(var + 1e-5f);
  float4 g = g4[tid], be = be4[tid], o;
  o.x = fmaxf((v.x - mean) * inv * g.x + be.x, 0.0f);
  o.y = fmaxf((v.y - mean) * inv * g.y + be.y, 0.0f);
  o.z = fmaxf((v.z - mean) * inv * g.z + be.z, 0.0f);
  o.w = fmaxf((v.w - mean) * inv * g.w + be.w, 0.0f);
  ((float4*)(h + path * 8192 + b * DD))[tid] = o;
}

// path0: mu_q; path1: sigma_q = softplus+1e-6, isig = 1/sigma
__global__ __launch_bounds__(256) void k_gemv_mid(const float* __restrict__ h,
    const float* __restrict__ W0, const float* __restrict__ W1,
    const float* __restrict__ b0, const float* __restrict__ b1,
    float* __restrict__ mu_out, float* __restrict__ sg_out, float* __restrict__ isig) {
  __shared__ float s_in[8][DD];
  int path = blockIdx.x >> 8;
  int row = (blockIdx.x & 255) * 4 + (threadIdx.x >> 6);
  const float* W = path ? W1 : W0;
  const float* bb = path ? b1 : b0;
  float acc[8];
  gemv_rows_core(h + path * 8192, W, row, s_in, acc);
  if ((threadIdx.x & 63) == 0) {
    float bv = bb[row];
#pragma unroll
    for (int b = 0; b < 8; ++b) {
      float v = acc[b] + bv;
      if (path == 0) {
        mu_out[b * DD + row] = v;
      } else {
        float sp = softplus_f(v) + 1e-6f;
        sg_out[b * DD + row] = sp;
        isig[b * DD + row] = 1.0f / sp;
      }
    }
  }
}

// q[b,row] = mu_q[b]·wq[row] + bq[row]   (wq = in_w rows 0..1023)
__global__ __launch_bounds__(256) void k_gemv_q(const float* __restrict__ mu_q,
    const float* __restrict__ in_w, const float* __restrict__ in_b, float* __restrict__ q) {
  __shared__ float s_in[8][DD];
  int row = blockIdx.x * 4 + (threadIdx.x >> 6);
  float acc[8];
  gemv_rows_core(mu_q, in_w, row, s_in, acc);
  if ((threadIdx.x & 63) == 0) {
    float bv = in_b[row];
#pragma unroll
    for (int b = 0; b < 8; ++b) q[b * DD + row] = acc[b] + bv;
  }
}

// p[b,h,j] = (sum_r q[b,h*128+r]*wk[h*128+r,j]) / sqrt(128)
// NOTE: the k-bias term q·bk is constant over t -> softmax-invariant -> dropped.
// Block 0 also zero-inits the exp-sum accumulator and loss (stream-ordered before k_main).
// r-loop unrolled 8x: 8 loads in flight instead of 1 (was a 128-deep serial chain).
__global__ __launch_bounds__(256) void k_p(const float* __restrict__ q,
    const float* __restrict__ in_w, float* __restrict__ p,
    float* __restrict__ sums, float* __restrict__ loss_out) {
  if (blockIdx.x == 0) {
    if (threadIdx.x < 64) sums[threadIdx.x] = 0.0f;
    else if (threadIdx.x == 64) loss_out[0] = 0.0f;
  }
  int hh = blockIdx.x >> 2;
  int j0 = (blockIdx.x & 3) * 256;
  __shared__ float qh[8][128];
  for (int i = threadIdx.x; i < 1024; i += 256) {
    int b = i >> 7, r = i & 127;
    qh[b][r] = q[b * DD + hh * 128 + r];
  }
  __syncthreads();
  const float* wbase = in_w + (size_t)(DD + hh * 128) * DD + j0 + threadIdx.x;
  float acc[8];
#pragma unroll
  for (int b = 0; b < 8; ++b) acc[b] = 0.0f;
#pragma unroll 8
  for (int r = 0; r < 128; ++r) {
    float w = wbase[(size_t)r * DD];
#pragma unroll
    for (int b = 0; b < 8; ++b) acc[b] += qh[b][r] * w;
  }
#pragma unroll
  for (int b = 0; b < 8; ++b) p[(b * HH + hh) * DD + j0 + threadIdx.x] = acc[b] * INV_SQRT_DH;
}

// Big streaming pass: dist[b,t] (f64 acc) and es[b,h,t] = exp(score) + per-(b,h) sums.
// r4 shape (79us): 512 blocks x 512 thr (8 waves), 64 rows/block via tg x2.
// launch_bounds(512,4): 128-VGPR cap (restores r3's ~52-reg load batching at r4's
// occupancy; (512,8)'s 64-reg cap crushed ILP -> 107us in r5).
// Video loads are NONTEMPORAL (read-once stream, via native ext_vector_type(4) —
// __builtin_nontemporal_load rejects HIP_vector_type): don't allocate in L2/L3,
// stop polluting the cache path that was capping the stream at ~1.7 TB/s.
__global__ __launch_bounds__(512, 4) void k_main(const float* __restrict__ video,
    const float* __restrict__ mu_q, const float* __restrict__ isig,
    const float* __restrict__ p,
    float* __restrict__ dist_out, float* __restrict__ es, float* __restrict__ sums) {
  __shared__ float s_mu[DD];     // 4 KB
  __shared__ float s_is[DD];     // 4 KB
  __shared__ float s_p[HH][DD];  // 32 KB  (total 40960 B)
  int b = blockIdx.x >> 6;
  int group = blockIdx.x & 63;
  int tid = threadIdx.x;
  int wave = tid >> 6, lane = tid & 63;
  int quarter = lane >> 4;   // which of the wave's 4 t-rows
  int sub = lane & 15;       // d-slice within the quarter
  float4* s_mu4 = (float4*)s_mu;
  float4* s_is4 = (float4*)s_is;
  float4* s_p4 = (float4*)&s_p[0][0];
  if (tid < 256) {
    s_mu4[tid] = ((const float4*)(mu_q + b * DD))[tid];
    s_is4[tid] = ((const float4*)(isig + b * DD))[tid];
  }
  const float4* pg4 = (const float4*)(p + b * HH * DD);
  for (int i = tid; i < 2048; i += 512) s_p4[i] = pg4[i];
  __syncthreads();

  float esum_acc = 0.0f;  // valid on lanes with sub<8 (head = sub)

#pragma unroll 1
  for (int tg = 0; tg < 2; ++tg) {
    int t = group * 64 + tg * 32 + wave * 4 + quarter;
    const floatx4* v4 = (const floatx4*)(video + ((size_t)(b * TT + t)) * DD);

    double dacc = 0.0;
    float sacc[8];
#pragma unroll
    for (int hh = 0; hh < 8; ++hh) sacc[hh] = 0.0f;

#pragma unroll 4
    for (int i = 0; i < 16; ++i) {
      int d4 = i * 16 + sub;
      floatx4 vv = __builtin_nontemporal_load(&v4[d4]);
      float4 mu4 = s_mu4[d4];
      float4 is4 = s_is4[d4];
      float dx = vv.x - mu4.x;
      float dy = vv.y - mu4.y;
      float dz = vv.z - mu4.z;
      float dw = vv.w - mu4.w;
      float e = dx * dx * is4.x + dy * dy * is4.y + dz * dz * is4.z + dw * dw * is4.w;
      dacc += (double)e;
#pragma unroll
      for (int hh = 0; hh < 8; ++hh) {
        float4 pp = ((const float4*)&s_p[hh][0])[d4];
        sacc[hh] += pp.x * vv.x + pp.y * vv.y + pp.z * vv.z + pp.w * vv.w;
      }
    }

    // butterfly within each 16-lane quarter (offsets 1,2,4,8)
#pragma unroll
    for (int off = 1; off < 16; off <<= 1) {
      dacc += __shfl_xor(dacc, off, 64);
#pragma unroll
      for (int hh = 0; hh < 8; ++hh) sacc[hh] += __shfl_xor(sacc[hh], off, 64);
    }

    if (sub == 0) dist_out[b * TT + t] = (float)dacc;
    if (sub < 8) {
      // static selection ladder: lane sub owns head sub
      float v = sacc[0];
#pragma unroll
      for (int hh = 1; hh < 8; ++hh) v = (sub == hh) ? sacc[hh] : v;
      float ev = expf(v);
      es[(size_t)(b * HH + sub) * TT + t] = ev;
      esum_acc += ev;
    }
  }

  // combine esum across quarters (same sub: lanes l, l^16, l^32, l^48)
  esum_acc += __shfl_xor(esum_acc, 16, 64);
  esum_acc += __shfl_xor(esum_acc, 32, 64);
  if (lane < 8) atomicAdd(&sums[b * HH + lane], esum_acc);
}

// Fused epilogue, one 1024-thread block per b:
//   attn mean from precomputed es/sums (single read) -> radix-select median
//   (wave-private histograms) -> combined (regs) -> greedy-K (all-register) ->
//   gather rep -> loss partial (atomicAdd).
__global__ __launch_bounds__(1024) void k_epilogue(const float* __restrict__ es,
    const float* __restrict__ sums,
    const float* __restrict__ dist, const float* __restrict__ video,
    float* __restrict__ comb_out, float* __restrict__ idx_out,
    float* __restrict__ rep, float* __restrict__ loss_out) {
  int b = blockIdx.x;
  int tid = threadIdx.x;
  int wave = tid >> 6, lane = tid & 63;
  __shared__ float s_dist[TT];            // 16 KB
  __shared__ float s_hs[HH];
  __shared__ unsigned whist[16][256];     // 16 KB wave-private histograms
  __shared__ unsigned wsum[4];
  __shared__ unsigned s_sel;
  __shared__ int s_kk;
  __shared__ float wv[16];
  __shared__ int wi[16];
  __shared__ int s_pick;
  __shared__ float wdiv[16];
  __shared__ float repb[KK * DD];         // 24 KB

  if (tid < HH) s_hs[tid] = 1.0f / sums[b * HH + tid];
  __syncthreads();

  // ---- attn mean + stage dist (one float4 per thread) ----
  float4 d4 = ((const float4*)(dist + b * TT))[tid];
  ((float4*)s_dist)[tid] = d4;
  float4 aw = make_float4(0.f, 0.f, 0.f, 0.f);
#pragma unroll
  for (int h = 0; h < HH; ++h) {
    float4 e4 = ((const float4*)(es + ((size_t)(b * HH + h)) * TT))[tid];
    float is = s_hs[h];
    aw.x += e4.x * is;
    aw.y += e4.y * is;
    aw.z += e4.z * is;
    aw.w += e4.w * is;
  }
  aw.x *= 0.125f; aw.y *= 0.125f; aw.z *= 0.125f; aw.w *= 0.125f;
  uint4 keys;
  keys.x = __float_as_uint(d4.x);
  keys.y = __float_as_uint(d4.y);
  keys.z = __float_as_uint(d4.z);
  keys.w = __float_as_uint(d4.w);

  // ---- radix-select median: rank 2047 (positive floats ~ uint order) ----
  unsigned prefix = 0;
  int kk = (TT - 1) / 2;
  for (int pass = 0; pass < 4; ++pass) {
    int shift = 24 - 8 * pass;
    ((uint4*)whist)[tid] = make_uint4(0u, 0u, 0u, 0u);  // 1024 threads x 16B = 16 KB
    __syncthreads();
    {
      unsigned karr[4] = {keys.x, keys.y, keys.z, keys.w};
#pragma unroll
      for (int j = 0; j < 4; ++j) {
        unsigned key = karr[j];
        bool ok = (pass == 0) || ((key >> (shift + 8)) == prefix);
        if (ok) atomicAdd(&whist[wave][(key >> shift) & 255], 1u);
      }
    }
    __syncthreads();
    unsigned hcnt = 0, inc = 0;
    if (tid < 256) {
#pragma unroll
      for (int w = 0; w < 16; ++w) hcnt += whist[w][tid];
      inc = hcnt;
#pragma unroll
      for (int off = 1; off < 64; off <<= 1) {
        unsigned v = __shfl_up(inc, off, 64);
        if (lane >= off) inc += v;
      }
      if (lane == 63) wsum[wave] = inc;
    }
    __syncthreads();
    if (tid < 256) {
      unsigned base = 0;
      for (int w = 0; w < wave; ++w) base += wsum[w];
      unsigned excl = base + inc - hcnt;
      if ((int)excl <= kk && kk < (int)(excl + hcnt)) {
        s_sel = (prefix << 8) | (unsigned)tid;
        s_kk = kk - (int)excl;
      }
    }
    __syncthreads();
    prefix = s_sel;
    kk = s_kk;
    __syncthreads();
  }
  float med = __uint_as_float(prefix);

  // ---- combined (registers) + global write ----
  float4 cb;
  cb.x = expf(-fabsf(d4.x - med) / 0.1f) * aw.x;
  cb.y = expf(-fabsf(d4.y - med) / 0.1f) * aw.y;
  cb.z = expf(-fabsf(d4.z - med) / 0.1f) * aw.z;
  cb.w = expf(-fabsf(d4.w - med) / 0.1f) * aw.w;
  ((float4*)(comb_out + b * TT))[tid] = cb;

  // ---- greedy K-selection, all-register (first-occurrence argmax) ----
  float4 md = make_float4(0.f, 0.f, 0.f, 0.f);
  int i0 = tid * 4;
  int picks[KK];
  for (int k = 0; k < KK; ++k) {
    float carr[4] = {cb.x, cb.y, cb.z, cb.w};
    float marr[4] = {md.x, md.y, md.z, md.w};
    float best = -INFINITY; int bi = 1 << 30;
#pragma unroll
    for (int j = 0; j < 4; ++j) {
      float cv = carr[j];
      float sc = (k == 0) ? cv : ((cv < 0.0f) ? -INFINITY : marr[j] * cv);
      if (sc > best) { best = sc; bi = i0 + j; }
    }
#pragma unroll
    for (int off = 32; off; off >>= 1) {
      float ov = __shfl_xor(best, off, 64);
      int oi = __shfl_xor(bi, off, 64);
      if (ov > best || (ov == best && oi < bi)) { best = ov; bi = oi; }
    }
    if (lane == 0) { wv[wave] = best; wi[wave] = bi; }
    __syncthreads();
    if (tid == 0) {
      float bb2 = wv[0]; int ii = wi[0];
#pragma unroll
      for (int w = 1; w < 16; ++w)
        if (wv[w] > bb2 || (wv[w] == bb2 && wi[w] < ii)) { bb2 = wv[w]; ii = wi[w]; }
      s_pick = ii;
    }
    __syncthreads();
    int pick = s_pick;
    picks[k] = pick;
    // mask in registers (owning thread only) + update min-dist in registers
    if ((pick >> 2) == tid) {
      int j = pick & 3;
      if (j == 0) cb.x = -1.0f; else if (j == 1) cb.y = -1.0f;
      else if (j == 2) cb.z = -1.0f; else cb.w = -1.0f;
    }
    float dn0 = fabsf((float)(i0 + 0 - pick));
    float dn1 = fabsf((float)(i0 + 1 - pick));
    float dn2 = fabsf((float)(i0 + 2 - pick));
    float dn3 = fabsf((float)(i0 + 3 - pick));
    if (k == 0) { md.x = dn0; md.y = dn1; md.z = dn2; md.w = dn3; }
    else { md.x = fminf(md.x, dn0); md.y = fminf(md.y, dn1);
           md.z = fminf(md.z, dn2); md.w = fminf(md.w, dn3); }
  }
  if (tid < KK) idx_out[b * KK + tid] = (float)picks[tid];

  // ---- gather rep ----
  float4* repb4 = (float4*)repb;
  float4* rep4 = (float4*)(rep + (size_t)b * KK * DD);
  for (int e = tid; e < KK * (DD / 4); e += 1024) {
    int k = e >> 8, dd4 = e & 255;
    const float4* vrow = (const float4*)(video + ((size_t)(b * TT + picks[k])) * DD);
    float4 v = vrow[dd4];
    rep4[(size_t)k * (DD / 4) + dd4] = v;
    repb4[e] = v;
  }
  __syncthreads();

  // ---- diversity: 15 pairs over 16 waves ----
  const int pk[15] = {0,0,0,0,0,1,1,1,1,2,2,2,3,3,4};
  const int pj[15] = {1,2,3,4,5,2,3,4,5,3,4,5,4,5,5};
  float divacc = 0.0f;
  if (wave < 15) {
    int a = pk[wave], j = pj[wave];
    float part = 0.0f;
    for (int d = lane; d < DD; d += 64) part += repb[a * DD + d] * repb[j * DD + d];
#pragma unroll
    for (int off = 32; off; off >>= 1) part += __shfl_xor(part, off, 64);
    if (lane == 0) divacc = part * part;
  }
  if (lane == 0) wdiv[wave] = (wave < 15) ? divacc : 0.0f;
  __syncthreads();

  if (tid == 0) {
    float div = 0.0f;
#pragma unroll
    for (int w = 0; w < 15; ++w) div += wdiv[w];
    float rd[KK], srt[KK];
#pragma unroll
    for (int k = 0; k < KK; ++k) { rd[k] = s_dist[picks[k]]; srt[k] = rd[k]; }
    for (int a = 1; a < KK; ++a) {
      float key = srt[a]; int b2 = a - 1;
      while (b2 >= 0 && srt[b2] > key) { srt[b2 + 1] = srt[b2]; --b2; }
      srt[b2 + 1] = key;
    }
    float target = srt[(KK - 1) / 2];
    float ell = 0.0f, cons = 0.0f;
#pragma unroll
    for (int k = 0; k < KK; ++k) { float d = rd[k] - target; ell += d * d; cons += rd[k]; }
    float partial = ell * (1.0f / 48.0f) + 0.1f * cons * (1.0f / 48.0f) + 0.05f * div * (1.0f / 288.0f);
    atomicAdd(loss_out, partial);
  }
}

extern "C" void kernel_launch(void* const* d_in, const int* in_sizes, int n_in,
                              void* d_out, int out_size, void* d_ws, size_t ws_size,
                              hipStream_t stream) {
  const float* video = (const float*)d_in[0];
  const float* qe    = (const float*)d_in[1];
  const float* mu_w1 = (const float*)d_in[2];
  const float* mu_b1 = (const float*)d_in[3];
  const float* mu_g  = (const float*)d_in[4];
  const float* mu_be = (const float*)d_in[5];
  const float* mu_w2 = (const float*)d_in[6];
  const float* mu_b2 = (const float*)d_in[7];
  const float* sg_w1 = (const float*)d_in[8];
  const float* sg_b1 = (const float*)d_in[9];
  const float* sg_g  = (const float*)d_in[10];
  const float* sg_be = (const float*)d_in[11];
  const float* sg_w2 = (const float*)d_in[12];
  const float* sg_b2 = (const float*)d_in[13];
  const float* in_w  = (const float*)d_in[14];
  const float* in_b  = (const float*)d_in[15];
  float* out = (float*)d_out;
  float* ws  = (float*)d_ws;

  k_gemv_pre<<<512, 256, 0, stream>>>(qe, mu_w1, sg_w1, mu_b1, sg_b1, ws + WS_X1);
  k_ln<<<16, 256, 0, stream>>>(ws + WS_X1, mu_g, mu_be, sg_g, sg_be, ws + WS_H);
  k_gemv_mid<<<512, 256, 0, stream>>>(ws + WS_H, mu_w2, sg_w2, mu_b2, sg_b2,
                                      out + OFF_MU, out + OFF_SG, ws + WS_ISIG);
  k_gemv_q<<<256, 256, 0, stream>>>(out + OFF_MU, in_w, in_b, ws + WS_Q);
  k_p<<<32, 256, 0, stream>>>(ws + WS_Q, in_w, ws + WS_P, ws + WS_SUMS, out + OFF_LOSS);
  k_main<<<512, 512, 0, stream>>>(video, out + OFF_MU, ws + WS_ISIG, ws + WS_P,
                                  out + OFF_DIST, ws + WS_ES, ws + WS_SUMS);
  k_epilogue<<<8, 1024, 0, stream>>>(ws + WS_ES, ws + WS_SUMS, out + OFF_DIST, video,
                                     out + OFF_COMB, out + OFF_IDX, out + OFF_REP, out + OFF_LOSS);
}

// Round 8
// 313.231 us; speedup vs baseline: 1.1413x; 1.0317x over previous
//
#include <hip/hip_runtime.h>
#include <math.h>

// ---------------- problem constants ----------------
#define BD   8       // batch
#define TT   4096    // time
#define DD   1024    // feature dim
#define HH   8       // heads
#define KK   6       // picks
// d_out layout (floats): rep | indices | combined | dist | mu_q | sigma_q | loss
#define OFF_REP   0
#define OFF_IDX   49152
#define OFF_COMB  49200
#define OFF_DIST  81968
#define OFF_MU    114736
#define OFF_SG    122928
#define OFF_LOSS  131120
// ws layout (floats)
#define WS_X1     0        // 2*8*1024
#define WS_H      16384    // 2*8*1024
#define WS_Q      32768    // 8*1024
#define WS_P      40960    // 8*8*1024
#define WS_SUMS   106496   // 64  (per b,h sum of exp(score))
#define WS_ISIG   106560   // 8*1024
#define WS_ES     114752   // 8*8*4096  (exp(score))

#define INV_SQRT_DH 0.08838834764831845f  // 1/sqrt(128)

typedef float floatx4 __attribute__((ext_vector_type(4)));  // native vec for NT loads

__device__ __forceinline__ float softplus_f(float x) {
  return fmaxf(x, 0.0f) + log1pf(expf(-fabsf(x)));
}

// ---- shared GEMV core: out[b,row] = in[b,:] . W[row,:]  (8 batches, wave per row)
__device__ __forceinline__ void gemv_rows_core(const float* __restrict__ in,
                                               const float* __restrict__ W,
                                               int row, float (*s_in)[DD], float acc[8]) {
  int tid = threadIdx.x;
  const float4* in4 = (const float4*)in;
  float4* s4 = (float4*)&s_in[0][0];
  for (int i = tid; i < 2048; i += 256) s4[i] = in4[i];
  __syncthreads();
  int lane = tid & 63;
  const float4* wr4 = (const float4*)(W + (size_t)row * DD);
#pragma unroll
  for (int b = 0; b < 8; ++b) acc[b] = 0.0f;
#pragma unroll
  for (int i = 0; i < 4; ++i) {
    int d4 = i * 64 + lane;
    float4 w4 = wr4[d4];
#pragma unroll
    for (int b = 0; b < 8; ++b) {
      float4 q4 = ((const float4*)&s_in[b][0])[d4];
      acc[b] += w4.x * q4.x + w4.y * q4.y + w4.z * q4.z + w4.w * q4.w;
    }
  }
#pragma unroll
  for (int off = 32; off; off >>= 1)
#pragma unroll
    for (int b = 0; b < 8; ++b) acc[b] += __shfl_xor(acc[b], off, 64);
}

// x1[path][b][row] = qe[b]·W{path}[row] + bias
__global__ __launch_bounds__(256) void k_gemv_pre(const float* __restrict__ qe,
    const float* __restrict__ W0, const float* __restrict__ W1,
    const float* __restrict__ b0, const float* __restrict__ b1, float* __restrict__ x1) {
  __shared__ float s_in[8][DD];
  int path = blockIdx.x >> 8;
  int row = (blockIdx.x & 255) * 4 + (threadIdx.x >> 6);
  const float* W = path ? W1 : W0;
  const float* bb = path ? b1 : b0;
  float acc[8];
  gemv_rows_core(qe, W, row, s_in, acc);
  if ((threadIdx.x & 63) == 0) {
    float bv = bb[row];
#pragma unroll
    for (int b = 0; b < 8; ++b) x1[path * 8192 + b * DD + row] = acc[b] + bv;
  }
}

// LN + relu per (path,b) row of 1024 — single-pass (sum, sumsq) + shuffle reduce
__global__ __launch_bounds__(256) void k_ln(const float* __restrict__ x1,
    const float* __restrict__ g0, const float* __restrict__ be0,
    const float* __restrict__ g1, const float* __restrict__ be1, float* __restrict__ h) {
  int path = blockIdx.x >> 3, b = blockIdx.x & 7;
  const float4* x4 = (const float4*)(x1 + path * 8192 + b * DD);
  const float4* g4 = (const float4*)(path ? g1 : g0);
  const float4* be4 = (const float4*)(path ? be1 : be0);
  int tid = threadIdx.x, wave = tid >> 6, lane = tid & 63;
  __shared__ float ws1[4], ws2[4];
  float4 v = x4[tid];
  float s = v.x + v.y + v.z + v.w;
  float s2 = v.x * v.x + v.y * v.y + v.z * v.z + v.w * v.w;
#pragma unroll
  for (int off = 32; off; off >>= 1) {
    s += __shfl_xor(s, off, 64);
    s2 += __shfl_xor(s2, off, 64);
  }
  if (lane == 0) { ws1[wave] = s; ws2[wave] = s2; }
  __syncthreads();
  s = ws1[0] + ws1[1] + ws1[2] + ws1[3];
  s2 = ws2[0] + ws2[1] + ws2[2] + ws2[3];
  float mean = s * (1.0f / 1024.0f);
  float var = s2 * (1.0f / 1024.0f) - mean * mean;
  float inv = 1.0f / sqrtf(var + 1e-5f);
  float4 g = g4[tid], be = be4[tid], o;
  o.x = fmaxf((v.x - mean) * inv * g.x + be.x, 0.0f);
  o.y = fmaxf((v.y - mean) * inv * g.y + be.y, 0.0f);
  o.z = fmaxf((v.z - mean) * inv * g.z + be.z, 0.0f);
  o.w = fmaxf((v.w - mean) * inv * g.w + be.w, 0.0f);
  ((float4*)(h + path * 8192 + b * DD))[tid] = o;
}

// path0: mu_q; path1: sigma_q = softplus+1e-6, isig = 1/sigma
__global__ __launch_bounds__(256) void k_gemv_mid(const float* __restrict__ h,
    const float* __restrict__ W0, const float* __restrict__ W1,
    const float* __restrict__ b0, const float* __restrict__ b1,
    float* __restrict__ mu_out, float* __restrict__ sg_out, float* __restrict__ isig) {
  __shared__ float s_in[8][DD];
  int path = blockIdx.x >> 8;
  int row = (blockIdx.x & 255) * 4 + (threadIdx.x >> 6);
  const float* W = path ? W1 : W0;
  const float* bb = path ? b1 : b0;
  float acc[8];
  gemv_rows_core(h + path * 8192, W, row, s_in, acc);
  if ((threadIdx.x & 63) == 0) {
    float bv = bb[row];
#pragma unroll
    for (int b = 0; b < 8; ++b) {
      float v = acc[b] + bv;
      if (path == 0) {
        mu_out[b * DD + row] = v;
      } else {
        float sp = softplus_f(v) + 1e-6f;
        sg_out[b * DD + row] = sp;
        isig[b * DD + row] = 1.0f / sp;
      }
    }
  }
}

// q[b,row] = mu_q[b]·wq[row] + bq[row]   (wq = in_w rows 0..1023)
__global__ __launch_bounds__(256) void k_gemv_q(const float* __restrict__ mu_q,
    const float* __restrict__ in_w, const float* __restrict__ in_b, float* __restrict__ q) {
  __shared__ float s_in[8][DD];
  int row = blockIdx.x * 4 + (threadIdx.x >> 6);
  float acc[8];
  gemv_rows_core(mu_q, in_w, row, s_in, acc);
  if ((threadIdx.x & 63) == 0) {
    float bv = in_b[row];
#pragma unroll
    for (int b = 0; b < 8; ++b) q[b * DD + row] = acc[b] + bv;
  }
}

// p[b,h,j] = (sum_r q[b,h*128+r]*wk[h*128+r,j]) / sqrt(128)
// NOTE: the k-bias term q·bk is constant over t -> softmax-invariant -> dropped.
// Block 0 also zero-inits the exp-sum accumulator and loss (stream-ordered before k_main).
// r-loop unrolled 8x: 8 loads in flight instead of 1 (was a 128-deep serial chain).
__global__ __launch_bounds__(256) void k_p(const float* __restrict__ q,
    const float* __restrict__ in_w, float* __restrict__ p,
    float* __restrict__ sums, float* __restrict__ loss_out) {
  if (blockIdx.x == 0) {
    if (threadIdx.x < 64) sums[threadIdx.x] = 0.0f;
    else if (threadIdx.x == 64) loss_out[0] = 0.0f;
  }
  int hh = blockIdx.x >> 2;
  int j0 = (blockIdx.x & 3) * 256;
  __shared__ float qh[8][128];
  for (int i = threadIdx.x; i < 1024; i += 256) {
    int b = i >> 7, r = i & 127;
    qh[b][r] = q[b * DD + hh * 128 + r];
  }
  __syncthreads();
  const float* wbase = in_w + (size_t)(DD + hh * 128) * DD + j0 + threadIdx.x;
  float acc[8];
#pragma unroll
  for (int b = 0; b < 8; ++b) acc[b] = 0.0f;
#pragma unroll 8
  for (int r = 0; r < 128; ++r) {
    float w = wbase[(size_t)r * DD];
#pragma unroll
    for (int b = 0; b < 8; ++b) acc[b] += qh[b][r] * w;
  }
#pragma unroll
  for (int b = 0; b < 8; ++b) p[(b * HH + hh) * DD + j0 + threadIdx.x] = acc[b] * INV_SQRT_DH;
}

// Big streaming pass: dist[b,t] (f64 acc) and es[b,h,t] = exp(score) + per-(b,h) sums.
// 1024 blocks x 512 thr (8 waves), 32 rows/block: grid/CU = 4 blocks, LDS 4x40960 =
// 163840 B = full CU -> 32 waves/CU possible. launch_bounds(512,4) = 128-VGPR cap;
// body compiles to ~52 VGPR (r3) <= 64 -> HW allows 8 waves/SIMD. This is the r5
// config minus its fatal (512,8) 20-VGPR squeeze.
// Video loads NONTEMPORAL (read-once stream): keep L2/L3 for p/mu/isig broadcasts.
// esum: block-level LDS reduction -> 8 global atomics/block (grid doubled; keeps
// total same-line atomics at 8k instead of 65k).
__global__ __launch_bounds__(512, 4) void k_main(const float* __restrict__ video,
    const float* __restrict__ mu_q, const float* __restrict__ isig,
    const float* __restrict__ p,
    float* __restrict__ dist_out, float* __restrict__ es, float* __restrict__ sums) {
  __shared__ float s_mu[DD];     // 4 KB
  __shared__ float s_is[DD];     // 4 KB
  __shared__ float s_p[HH][DD];  // 32 KB  (total 40960 B + s_esum)
  __shared__ float s_esum[HH];
  int b = blockIdx.x >> 7;
  int group = blockIdx.x & 127;
  int tid = threadIdx.x;
  int wave = tid >> 6, lane = tid & 63;
  int quarter = lane >> 4;   // which of the wave's 4 t-rows
  int sub = lane & 15;       // d-slice within the quarter
  float4* s_mu4 = (float4*)s_mu;
  float4* s_is4 = (float4*)s_is;
  float4* s_p4 = (float4*)&s_p[0][0];
  if (tid < 256) {
    s_mu4[tid] = ((const float4*)(mu_q + b * DD))[tid];
    s_is4[tid] = ((const float4*)(isig + b * DD))[tid];
  }
  const float4* pg4 = (const float4*)(p + b * HH * DD);
  for (int i = tid; i < 2048; i += 512) s_p4[i] = pg4[i];
  if (tid < HH) s_esum[tid] = 0.0f;
  __syncthreads();

  int t = group * 32 + wave * 4 + quarter;
  const floatx4* v4 = (const floatx4*)(video + ((size_t)(b * TT + t)) * DD);

  double dacc = 0.0;
  float sacc[8];
#pragma unroll
  for (int hh = 0; hh < 8; ++hh) sacc[hh] = 0.0f;

#pragma unroll 4
  for (int i = 0; i < 16; ++i) {
    int d4 = i * 16 + sub;
    floatx4 vv = __builtin_nontemporal_load(&v4[d4]);
    float4 mu4 = s_mu4[d4];
    float4 is4 = s_is4[d4];
    float dx = vv.x - mu4.x;
    float dy = vv.y - mu4.y;
    float dz = vv.z - mu4.z;
    float dw = vv.w - mu4.w;
    float e = dx * dx * is4.x + dy * dy * is4.y + dz * dz * is4.z + dw * dw * is4.w;
    dacc += (double)e;
#pragma unroll
    for (int hh = 0; hh < 8; ++hh) {
      float4 pp = ((const float4*)&s_p[hh][0])[d4];
      sacc[hh] += pp.x * vv.x + pp.y * vv.y + pp.z * vv.z + pp.w * vv.w;
    }
  }

  // butterfly within each 16-lane quarter (offsets 1,2,4,8)
#pragma unroll
  for (int off = 1; off < 16; off <<= 1) {
    dacc += __shfl_xor(dacc, off, 64);
#pragma unroll
    for (int hh = 0; hh < 8; ++hh) sacc[hh] += __shfl_xor(sacc[hh], off, 64);
  }

  if (sub == 0) dist_out[b * TT + t] = (float)dacc;
  if (sub < 8) {
    // static selection ladder: lane sub owns head sub
    float v = sacc[0];
#pragma unroll
    for (int hh = 1; hh < 8; ++hh) v = (sub == hh) ? sacc[hh] : v;
    float ev = expf(v);
    es[(size_t)(b * HH + sub) * TT + t] = ev;
    atomicAdd(&s_esum[sub], ev);
  }
  __syncthreads();
  if (tid < HH) atomicAdd(&sums[b * HH + tid], s_esum[tid]);
}

// Fused epilogue, one 1024-thread block per b:
//   attn mean from precomputed es/sums (single read) -> radix-select median
//   (wave-private histograms) -> combined (regs) -> greedy-K (all-register) ->
//   gather rep -> loss partial (atomicAdd).
__global__ __launch_bounds__(1024) void k_epilogue(const float* __restrict__ es,
    const float* __restrict__ sums,
    const float* __restrict__ dist, const float* __restrict__ video,
    float* __restrict__ comb_out, float* __restrict__ idx_out,
    float* __restrict__ rep, float* __restrict__ loss_out) {
  int b = blockIdx.x;
  int tid = threadIdx.x;
  int wave = tid >> 6, lane = tid & 63;
  __shared__ float s_dist[TT];            // 16 KB
  __shared__ float s_hs[HH];
  __shared__ unsigned whist[16][256];     // 16 KB wave-private histograms
  __shared__ unsigned wsum[4];
  __shared__ unsigned s_sel;
  __shared__ int s_kk;
  __shared__ float wv[16];
  __shared__ int wi[16];
  __shared__ int s_pick;
  __shared__ float wdiv[16];
  __shared__ float repb[KK * DD];         // 24 KB

  if (tid < HH) s_hs[tid] = 1.0f / sums[b * HH + tid];
  __syncthreads();

  // ---- attn mean + stage dist (one float4 per thread) ----
  float4 d4 = ((const float4*)(dist + b * TT))[tid];
  ((float4*)s_dist)[tid] = d4;
  float4 aw = make_float4(0.f, 0.f, 0.f, 0.f);
#pragma unroll
  for (int h = 0; h < HH; ++h) {
    float4 e4 = ((const float4*)(es + ((size_t)(b * HH + h)) * TT))[tid];
    float is = s_hs[h];
    aw.x += e4.x * is;
    aw.y += e4.y * is;
    aw.z += e4.z * is;
    aw.w += e4.w * is;
  }
  aw.x *= 0.125f; aw.y *= 0.125f; aw.z *= 0.125f; aw.w *= 0.125f;
  uint4 keys;
  keys.x = __float_as_uint(d4.x);
  keys.y = __float_as_uint(d4.y);
  keys.z = __float_as_uint(d4.z);
  keys.w = __float_as_uint(d4.w);

  // ---- radix-select median: rank 2047 (positive floats ~ uint order) ----
  unsigned prefix = 0;
  int kk = (TT - 1) / 2;
  for (int pass = 0; pass < 4; ++pass) {
    int shift = 24 - 8 * pass;
    ((uint4*)whist)[tid] = make_uint4(0u, 0u, 0u, 0u);  // 1024 threads x 16B = 16 KB
    __syncthreads();
    {
      unsigned karr[4] = {keys.x, keys.y, keys.z, keys.w};
#pragma unroll
      for (int j = 0; j < 4; ++j) {
        unsigned key = karr[j];
        bool ok = (pass == 0) || ((key >> (shift + 8)) == prefix);
        if (ok) atomicAdd(&whist[wave][(key >> shift) & 255], 1u);
      }
    }
    __syncthreads();
    unsigned hcnt = 0, inc = 0;
    if (tid < 256) {
#pragma unroll
      for (int w = 0; w < 16; ++w) hcnt += whist[w][tid];
      inc = hcnt;
#pragma unroll
      for (int off = 1; off < 64; off <<= 1) {
        unsigned v = __shfl_up(inc, off, 64);
        if (lane >= off) inc += v;
      }
      if (lane == 63) wsum[wave] = inc;
    }
    __syncthreads();
    if (tid < 256) {
      unsigned base = 0;
      for (int w = 0; w < wave; ++w) base += wsum[w];
      unsigned excl = base + inc - hcnt;
      if ((int)excl <= kk && kk < (int)(excl + hcnt)) {
        s_sel = (prefix << 8) | (unsigned)tid;
        s_kk = kk - (int)excl;
      }
    }
    __syncthreads();
    prefix = s_sel;
    kk = s_kk;
    __syncthreads();
  }
  float med = __uint_as_float(prefix);

  // ---- combined (registers) + global write ----
  float4 cb;
  cb.x = expf(-fabsf(d4.x - med) / 0.1f) * aw.x;
  cb.y = expf(-fabsf(d4.y - med) / 0.1f) * aw.y;
  cb.z = expf(-fabsf(d4.z - med) / 0.1f) * aw.z;
  cb.w = expf(-fabsf(d4.w - med) / 0.1f) * aw.w;
  ((float4*)(comb_out + b * TT))[tid] = cb;

  // ---- greedy K-selection, all-register (first-occurrence argmax) ----
  float4 md = make_float4(0.f, 0.f, 0.f, 0.f);
  int i0 = tid * 4;
  int picks[KK];
  for (int k = 0; k < KK; ++k) {
    float carr[4] = {cb.x, cb.y, cb.z, cb.w};
    float marr[4] = {md.x, md.y, md.z, md.w};
    float best = -INFINITY; int bi = 1 << 30;
#pragma unroll
    for (int j = 0; j < 4; ++j) {
      float cv = carr[j];
      float sc = (k == 0) ? cv : ((cv < 0.0f) ? -INFINITY : marr[j] * cv);
      if (sc > best) { best = sc; bi = i0 + j; }
    }
#pragma unroll
    for (int off = 32; off; off >>= 1) {
      float ov = __shfl_xor(best, off, 64);
      int oi = __shfl_xor(bi, off, 64);
      if (ov > best || (ov == best && oi < bi)) { best = ov; bi = oi; }
    }
    if (lane == 0) { wv[wave] = best; wi[wave] = bi; }
    __syncthreads();
    if (tid == 0) {
      float bb2 = wv[0]; int ii = wi[0];
#pragma unroll
      for (int w = 1; w < 16; ++w)
        if (wv[w] > bb2 || (wv[w] == bb2 && wi[w] < ii)) { bb2 = wv[w]; ii = wi[w]; }
      s_pick = ii;
    }
    __syncthreads();
    int pick = s_pick;
    picks[k] = pick;
    // mask in registers (owning thread only) + update min-dist in registers
    if ((pick >> 2) == tid) {
      int j = pick & 3;
      if (j == 0) cb.x = -1.0f; else if (j == 1) cb.y = -1.0f;
      else if (j == 2) cb.z = -1.0f; else cb.w = -1.0f;
    }
    float dn0 = fabsf((float)(i0 + 0 - pick));
    float dn1 = fabsf((float)(i0 + 1 - pick));
    float dn2 = fabsf((float)(i0 + 2 - pick));
    float dn3 = fabsf((float)(i0 + 3 - pick));
    if (k == 0) { md.x = dn0; md.y = dn1; md.z = dn2; md.w = dn3; }
    else { md.x = fminf(md.x, dn0); md.y = fminf(md.y, dn1);
           md.z = fminf(md.z, dn2); md.w = fminf(md.w, dn3); }
  }
  if (tid < KK) idx_out[b * KK + tid] = (float)picks[tid];

  // ---- gather rep ----
  float4* repb4 = (float4*)repb;
  float4* rep4 = (float4*)(rep + (size_t)b * KK * DD);
  for (int e = tid; e < KK * (DD / 4); e += 1024) {
    int k = e >> 8, dd4 = e & 255;
    const float4* vrow = (const float4*)(video + ((size_t)(b * TT + picks[k])) * DD);
    float4 v = vrow[dd4];
    rep4[(size_t)k * (DD / 4) + dd4] = v;
    repb4[e] = v;
  }
  __syncthreads();

  // ---- diversity: 15 pairs over 16 waves ----
  const int pk[15] = {0,0,0,0,0,1,1,1,1,2,2,2,3,3,4};
  const int pj[15] = {1,2,3,4,5,2,3,4,5,3,4,5,4,5,5};
  float divacc = 0.0f;
  if (wave < 15) {
    int a = pk[wave], j = pj[wave];
    float part = 0.0f;
    for (int d = lane; d < DD; d += 64) part += repb[a * DD + d] * repb[j * DD + d];
#pragma unroll
    for (int off = 32; off; off >>= 1) part += __shfl_xor(part, off, 64);
    if (lane == 0) divacc = part * part;
  }
  if (lane == 0) wdiv[wave] = (wave < 15) ? divacc : 0.0f;
  __syncthreads();

  if (tid == 0) {
    float div = 0.0f;
#pragma unroll
    for (int w = 0; w < 15; ++w) div += wdiv[w];
    float rd[KK], srt[KK];
#pragma unroll
    for (int k = 0; k < KK; ++k) { rd[k] = s_dist[picks[k]]; srt[k] = rd[k]; }
    for (int a = 1; a < KK; ++a) {
      float key = srt[a]; int b2 = a - 1;
      while (b2 >= 0 && srt[b2] > key) { srt[b2 + 1] = srt[b2]; --b2; }
      srt[b2 + 1] = key;
    }
    float target = srt[(KK - 1) / 2];
    float ell = 0.0f, cons = 0.0f;
#pragma unroll
    for (int k = 0; k < KK; ++k) { float d = rd[k] - target; ell += d * d; cons += rd[k]; }
    float partial = ell * (1.0f / 48.0f) + 0.1f * cons * (1.0f / 48.0f) + 0.05f * div * (1.0f / 288.0f);
    atomicAdd(loss_out, partial);
  }
}

extern "C" void kernel_launch(void* const* d_in, const int* in_sizes, int n_in,
                              void* d_out, int out_size, void* d_ws, size_t ws_size,
                              hipStream_t stream) {
  const float* video = (const float*)d_in[0];
  const float* qe    = (const float*)d_in[1];
  const float* mu_w1 = (const float*)d_in[2];
  const float* mu_b1 = (const float*)d_in[3];
  const float* mu_g  = (const float*)d_in[4];
  const float* mu_be = (const float*)d_in[5];
  const float* mu_w2 = (const float*)d_in[6];
  const float* mu_b2 = (const float*)d_in[7];
  const float* sg_w1 = (const float*)d_in[8];
  const float* sg_b1 = (const float*)d_in[9];
  const float* sg_g  = (const float*)d_in[10];
  const float* sg_be = (const float*)d_in[11];
  const float* sg_w2 = (const float*)d_in[12];
  const float* sg_b2 = (const float*)d_in[13];
  const float* in_w  = (const float*)d_in[14];
  const float* in_b  = (const float*)d_in[15];
  float* out = (float*)d_out;
  float* ws  = (float*)d_ws;

  k_gemv_pre<<<512, 256, 0, stream>>>(qe, mu_w1, sg_w1, mu_b1, sg_b1, ws + WS_X1);
  k_ln<<<16, 256, 0, stream>>>(ws + WS_X1, mu_g, mu_be, sg_g, sg_be, ws + WS_H);
  k_gemv_mid<<<512, 256, 0, stream>>>(ws + WS_H, mu_w2, sg_w2, mu_b2, sg_b2,
                                      out + OFF_MU, out + OFF_SG, ws + WS_ISIG);
  k_gemv_q<<<256, 256, 0, stream>>>(out + OFF_MU, in_w, in_b, ws + WS_Q);
  k_p<<<32, 256, 0, stream>>>(ws + WS_Q, in_w, ws + WS_P, ws + WS_SUMS, out + OFF_LOSS);
  k_main<<<1024, 512, 0, stream>>>(video, out + OFF_MU, ws + WS_ISIG, ws + WS_P,
                                   out + OFF_DIST, ws + WS_ES, ws + WS_SUMS);
  k_epilogue<<<8, 1024, 0, stream>>>(ws + WS_ES, ws + WS_SUMS, out + OFF_DIST, video,
                                     out + OFF_COMB, out + OFF_IDX, out + OFF_REP, out + OFF_LOSS);
}